// Round 9
// baseline (371.488 us; speedup 1.0000x reference)
//
#include <hip/hip_runtime.h>
#include <math.h>

#define NB 65536
#define ND 1280
#define NH 512
#define NT 4

typedef float f32x4 __attribute__((ext_vector_type(4)));
typedef float f32x2 __attribute__((ext_vector_type(2)));
typedef short s16x8 __attribute__((ext_vector_type(8)));
typedef unsigned int u32x2 __attribute__((ext_vector_type(2)));
typedef unsigned int u32x4 __attribute__((ext_vector_type(4)));
typedef unsigned long long ull;
typedef unsigned short u16;

static __device__ __forceinline__ unsigned f2bf1(float x) {
    union { float f; unsigned u; } v; v.f = x;
    return (v.u + 0x7fffu + ((v.u >> 16) & 1u)) >> 16;   // RNE f32 -> bf16 bits
}
static __device__ __forceinline__ unsigned packbf(float a, float b) {
    return f2bf1(a) | (f2bf1(b) << 16);
}
static __device__ __forceinline__ int swz(int a) {
    return a ^ (((a >> 7) & 7) << 4);
}
static __device__ __forceinline__ float gelu_exact(float x) {
    return 0.5f * x * (1.0f + erff(x * 0.70710678118654752f));
}

#define SCHEDB __builtin_amdgcn_sched_barrier(0)
#define WAITVM(N) do { asm volatile("s_waitcnt vmcnt(" #N ")" ::: "memory"); SCHEDB; } while (0)
#define WAITLG do { asm volatile("s_waitcnt lgkmcnt(0)" ::: "memory"); SCHEDB; } while (0)

// ---------------- W1 -> MFMA-fragment-ordered bf16 ----------------
// Wfrag[t][kt 20][cf 32][ks 2][lane 64][e 8]:
//   value = W1[t][k = kt*64 + ks*32 + (lane>>4)*8 + e][h = cf*16 + (lane&15)]
__global__ __launch_bounds__(256) void fragw_kernel(const float* __restrict__ W1,
                                                    u16* __restrict__ Wfrag) {
    __shared__ float tl[64][129];
    int b = blockIdx.x;                  // 320 = 4t * 20kt * 4cq
    int cq = b & 3, kt = (b >> 2) % 20, t = b / 80;
    int tid = threadIdx.x;
    const float* src = W1 + ((size_t)t * ND + kt * 64) * NH + cq * 128;
#pragma unroll
    for (int i = 0; i < 8; ++i) {
        int k = i * 8 + (tid >> 5), h4 = (tid & 31) * 4;
        f32x4 v = *(const f32x4*)(src + (size_t)k * NH + h4);
        tl[k][h4 + 0] = v[0]; tl[k][h4 + 1] = v[1];
        tl[k][h4 + 2] = v[2]; tl[k][h4 + 3] = v[3];
    }
    __syncthreads();
#pragma unroll
    for (int j = 0; j < 4; ++j) {
        int u = tid + 256 * j;
        int cfl = u >> 7, ks = (u >> 6) & 1, l = u & 63;
        int h = cfl * 16 + (l & 15);
        int kb = ks * 32 + (l >> 4) * 8;
        unsigned pk[4];
#pragma unroll
        for (int e = 0; e < 4; ++e)
            pk[e] = packbf(tl[kb + 2 * e][h], tl[kb + 2 * e + 1][h]);
        u16* dst = Wfrag + ((size_t)((t * 20 + kt) * 32 + cq * 8 + cfl) * 2 + ks) * 512 + l * 8;
        *(u32x4*)dst = (u32x4){pk[0], pk[1], pk[2], pk[3]};
    }
}

// ---------------- bucketing (atomic-free counting sort) ----------------
__global__ __launch_bounds__(256) void count_kernel(const int* __restrict__ idx,
                                                    int* __restrict__ bc) {
    int tid = threadIdx.x;
    int i = blockIdx.x * 256 + tid;
    int t = idx[i];
    int lane = tid & 63, wave = tid >> 6;
    ull b0 = __ballot(t & 1);
    ull b1 = __ballot(t & 2);
    ull mask = ((t & 1) ? b0 : ~b0) & ((t & 2) ? b1 : ~b1);
    int rank = __popcll(mask & ((1ULL << lane) - 1ULL));
    __shared__ int lc[4][4];
    if (tid < 16) ((int*)lc)[tid] = 0;
    __syncthreads();
    if (rank == 0) lc[wave][t] = __popcll(mask);
    __syncthreads();
    if (tid < 4)
        bc[blockIdx.x * 4 + tid] = lc[0][tid] + lc[1][tid] + lc[2][tid] + lc[3][tid];
}

__global__ __launch_bounds__(256) void scan_kernel(const int* __restrict__ bc,
        int* __restrict__ counts, int* __restrict__ base, int* __restrict__ tmap) {
    __shared__ int segtot[64][4];
    __shared__ int segbase[64][4];
    __shared__ int ttot[4];
    int tid = threadIdx.x;
    int t = tid & 3, seg = tid >> 2;
    int s0 = bc[(seg * 4 + 0) * 4 + t];
    int s1 = bc[(seg * 4 + 1) * 4 + t];
    int s2 = bc[(seg * 4 + 2) * 4 + t];
    int s3 = bc[(seg * 4 + 3) * 4 + t];
    segtot[seg][t] = s0 + s1 + s2 + s3;
    __syncthreads();
    if (tid < 4) {
        int run = 0;
        for (int g = 0; g < 64; ++g) { segbase[g][tid] = run; run += segtot[g][tid]; }
        ttot[tid] = run;
        counts[tid] = run;
    }
    __syncthreads();
    if (tid == 0) {     // tile map: prefix over ceil(cnt_t/128)
        int s = 0;
        tmap[0] = 0;
        for (int u = 0; u < 4; ++u) { s += (ttot[u] + 127) >> 7; tmap[u + 1] = s; }
    }
    int toff = 0;
    for (int u = 0; u < 4; ++u) toff += (u < t) ? ttot[u] : 0;
    int run = toff + segbase[seg][t];
    base[(seg * 4 + 0) * 4 + t] = run; run += s0;
    base[(seg * 4 + 1) * 4 + t] = run; run += s1;
    base[(seg * 4 + 2) * 4 + t] = run; run += s2;
    base[(seg * 4 + 3) * 4 + t] = run;
}

__global__ __launch_bounds__(256) void scatter_kernel(const int* __restrict__ idx,
        const int* __restrict__ base, int* __restrict__ perm,
        const float* __restrict__ b2, float* __restrict__ out) {
    int tid = threadIdx.x;
    int i = blockIdx.x * 256 + tid;
    int t = idx[i];
    int lane = tid & 63, wave = tid >> 6;
    ull b0 = __ballot(t & 1);
    ull b1 = __ballot(t & 2);
    ull mask = ((t & 1) ? b0 : ~b0) & ((t & 2) ? b1 : ~b1);
    int rank = __popcll(mask & ((1ULL << lane) - 1ULL));
    __shared__ int lc[4][4];
    if (tid < 16) ((int*)lc)[tid] = 0;
    __syncthreads();
    if (rank == 0) lc[wave][t] = __popcll(mask);
    __syncthreads();
    int pre = 0;
#pragma unroll
    for (int w = 0; w < 4; ++w) pre += (w < wave) ? lc[w][t] : 0;
    perm[base[blockIdx.x * 4 + t] + pre + rank] = i;
    out[i] = b2[t];   // init for atomic fallback path
}

// ---------------- consolidated routed GEMM + fused epilogue ----------------
// 128x128 block, 4 waves (2x2), wave 64x64, BK=64, 20 K-tiles.
// A: R3's proven gather (4 rows x 256B per wave-instr coalescing), f32 regs ->
//    packbf -> swizzled LDS (0-conflict layout, measured), DOUBLE-buffered.
// B: register fragments, one coalesced 1KB load each, from fragment-ordered
//    Wfrag (L2-resident). No B LDS, no B glds.
// One s_barrier + constant vmcnt(8) per K-tile; >=8 VMEM always in flight.
__global__ __launch_bounds__(256, 3) void gemm_c(
        const float* __restrict__ feat, const u16* __restrict__ Wfrag,
        const float* __restrict__ b1, const float* __restrict__ w2,
        const int* __restrict__ perm, const int* __restrict__ counts,
        const int* __restrict__ tmap,
        float* __restrict__ partials, float* __restrict__ out, int use_partials) {
    __shared__ char smem[32768];        // A buf0 @0, buf1 @16384: bf16 [128r][128B] swizzled

    int bx = blockIdx.x;
    int r8 = bx & 7, m8 = bx >> 3;
    int ct = m8 & 3;
    int tau = (m8 >> 2) * 8 + r8;       // 4 ct-siblings adjacent per XCD slot
    if (tau >= tmap[4]) return;
    int t = 0;
#pragma unroll
    for (int u = 0; u < 3; ++u) t += (tau >= tmap[u + 1]) ? 1 : 0;
    int tile_m = tau - tmap[t];
    int cnt = counts[t];
    int tilebase = tile_m * 128;
    int off_t = 0;
    for (int u = 0; u < t; ++u) off_t += counts[u];

    int tid = threadIdx.x;
    int lane = tid & 63, wid = tid >> 6;
    int wr = wid >> 1, wc = wid & 1;
    int rl = lane & 15, q0 = lane >> 4;
    int hc0 = ct * 128 + wc * 64;

    // ---- A gather offsets (R3 exact): row i*16+(tid>>4), chunk (tid&15)*16B ----
    unsigned aoff[8];
#pragma unroll
    for (int i = 0; i < 8; ++i) {
        int r = tilebase + i * 16 + (tid >> 4);
        if (r > cnt - 1) r = cnt - 1;
        aoff[i] = (unsigned)perm[off_t + r] * ND + (tid & 15) * 4;
    }

    // ---- B fragment base: Wfrag[t][kt][ct*8+wc*4+fn][ks][lane][8] ----
    const u16* bb = Wfrag + (size_t)t * 655360
                  + (unsigned)((ct * 8 + wc * 4) * 1024) + lane * 8;

    f32x4 acc[4][4];
#pragma unroll
    for (int a = 0; a < 4; ++a)
#pragma unroll
        for (int b = 0; b < 4; ++b) acc[a][b] = (f32x4){0.f, 0.f, 0.f, 0.f};

    f32x4 apf[8];
    s16x8 bF[4][2];

#define LOADA(KT) do {                                                          \
    _Pragma("unroll")                                                           \
    for (int i = 0; i < 8; ++i)                                                 \
        apf[i] = *(const f32x4*)(feat + aoff[i] + (KT) * 64);                   \
} while (0)

#define LOADB(KT) do {                                                          \
    _Pragma("unroll")                                                           \
    for (int fn = 0; fn < 4; ++fn)                                              \
        _Pragma("unroll")                                                       \
        for (int ks = 0; ks < 2; ++ks)                                          \
            bF[fn][ks] = *(const s16x8*)(bb + (KT) * 32768 + fn * 1024 + ks * 512); \
} while (0)

#define WRITEA(P) do {                                                          \
    char* ab_ = smem + (P) * 16384;                                             \
    _Pragma("unroll")                                                           \
    for (int i = 0; i < 8; ++i) {                                               \
        int row_ = i * 16 + (tid >> 4);                                         \
        u32x2 v_;                                                               \
        v_.x = packbf(apf[i][0], apf[i][1]);                                    \
        v_.y = packbf(apf[i][2], apf[i][3]);                                    \
        *(u32x2*)(ab_ + swz(row_ * 128 + (tid & 15) * 8)) = v_;                 \
    }                                                                           \
} while (0)

#define COMPUTE(P) do {                                                         \
    char* ab_ = smem + (P) * 16384;                                             \
    __builtin_amdgcn_s_setprio(1);                                              \
    _Pragma("unroll")                                                           \
    for (int ks = 0; ks < 2; ++ks) {                                            \
        int kbyte_ = ks * 64 + q0 * 16;                                         \
        s16x8 af_[4];                                                           \
        _Pragma("unroll")                                                       \
        for (int f = 0; f < 4; ++f) {                                           \
            int rowA_ = wr * 64 + f * 16 + rl;                                  \
            af_[f] = *(const s16x8*)(ab_ + swz(rowA_ * 128 + kbyte_));          \
        }                                                                       \
        _Pragma("unroll")                                                       \
        for (int fm = 0; fm < 4; ++fm)                                          \
            _Pragma("unroll")                                                   \
            for (int fn = 0; fn < 4; ++fn)                                      \
                acc[fm][fn] = __builtin_amdgcn_mfma_f32_16x16x32_bf16(          \
                    af_[fm], bF[fn][ks], acc[fm][fn], 0, 0, 0);                 \
    }                                                                           \
    __builtin_amdgcn_s_setprio(0);                                              \
} while (0)

    // ---- prologue: buf0 <- A(0); A(1) in flight; bF <- B(0) ----
    LOADA(0);
    LOADB(0);                         // out: A0:8 + B0:8
    WAITVM(8);                        // A0 landed
    WRITEA(0);
    LOADA(1);                         // out: B0:8 + A1:8
    WAITLG;
    WAITVM(8);                        // B0 landed; A1 in flight
    __builtin_amdgcn_s_barrier();

    // ---- steady: tiles 0..17 (2 per iteration, static parity) ----
#pragma unroll 1
    for (int kt = 0; kt < 18; kt += 2) {
        // tile kt (P=0). In flight at entry: A(kt+1):8
        COMPUTE(0);                   // A(kt) buf0, B(kt) regs
        LOADB(kt + 1);                // out: A(kt+1):8 + B(kt+1):8
        WAITVM(8);                    // A(kt+1) landed (oldest)
        WRITEA(1);
        LOADA(kt + 2);                // out: B(kt+1):8 + A(kt+2):8
        WAITLG;
        WAITVM(8);                    // B(kt+1) landed; A(kt+2) in flight
        __builtin_amdgcn_s_barrier();
        // tile kt+1 (P=1)
        COMPUTE(1);
        LOADB(kt + 2);
        WAITVM(8);
        WRITEA(0);
        LOADA(kt + 3);
        WAITLG;
        WAITVM(8);
        __builtin_amdgcn_s_barrier();
    }
    // ---- tile 18 (P=0); A(19) in flight ----
    COMPUTE(0);
    LOADB(19);                        // out: A19:8 + B19:8
    WAITVM(8);                        // A19 landed
    WRITEA(1);
    WAITLG;
    WAITVM(0);                        // B19 landed
    __builtin_amdgcn_s_barrier();
    // ---- tile 19 (P=1) ----
    COMPUTE(1);

#undef COMPUTE
#undef WRITEA
#undef LOADB
#undef LOADA

    // ---- epilogue: +b1, exact GELU, *w2, reduce over this wave's 64 cols ----
    float part[4][4];
#pragma unroll
    for (int mf = 0; mf < 4; ++mf)
#pragma unroll
        for (int r = 0; r < 4; ++r) part[mf][r] = 0.f;
#pragma unroll
    for (int nf = 0; nf < 4; ++nf) {
        int h = hc0 + nf * 16 + rl;
        float b1v = b1[t * NH + h];
        float w2v = w2[t * NH + h];
#pragma unroll
        for (int mf = 0; mf < 4; ++mf)
#pragma unroll
            for (int r = 0; r < 4; ++r) {
                float v = acc[mf][nf][r] + b1v;
                part[mf][r] += gelu_exact(v) * w2v;
            }
    }
#pragma unroll
    for (int m = 1; m <= 8; m <<= 1)
#pragma unroll
        for (int mf = 0; mf < 4; ++mf)
#pragma unroll
            for (int r = 0; r < 4; ++r)
                part[mf][r] += __shfl_xor(part[mf][r], m, 64);

    if (rl == 0) {
        int slot = ct * 2 + wc;
#pragma unroll
        for (int mf = 0; mf < 4; ++mf)
#pragma unroll
            for (int r = 0; r < 4; ++r) {
                int row = wr * 64 + mf * 16 + q0 * 4 + r;
                int gr = tilebase + row;
                if (gr < cnt) {
                    int s = perm[off_t + gr];
                    if (use_partials)
                        partials[(size_t)s * 8 + slot] = part[mf][r];
                    else
                        atomicAdd(&out[s], part[mf][r]);
                }
            }
    }
}

// ---------------- fallback (no-ws) path: R3 LDS kernel, strided f32 B ----------------
__global__ __launch_bounds__(256, 2) void gemm_fallback(
        const float* __restrict__ feat, const float* __restrict__ W1,
        const float* __restrict__ b1, const float* __restrict__ w2,
        const int* __restrict__ perm, const int* __restrict__ counts,
        float* __restrict__ partials, float* __restrict__ out, int use_partials) {
    __shared__ char smem[32768];
    int bx = blockIdx.x;
    int r8 = bx & 7, m8 = bx >> 3;
    int ct = m8 & 3, q = m8 >> 2;
    int g = q * 8 + r8;
    int t = g >> 9, tile_m = g & 511;
    int cnt = counts[t];
    int tilebase = tile_m * 128;
    if (tilebase >= cnt) return;
    int off_t = 0;
    for (int u = 0; u < t; ++u) off_t += counts[u];

    int tid = threadIdx.x;
    int lane = tid & 63, wave = tid >> 6;
    int wr = wave >> 1, wc = wave & 1;
    int hc0 = ct * 128;

    unsigned aoff[8];
#pragma unroll
    for (int i = 0; i < 8; ++i) {
        int r = tilebase + i * 16 + (tid >> 4);
        if (r > cnt - 1) r = cnt - 1;
        int s = perm[off_t + r];
        aoff[i] = (unsigned)s * ND + (tid & 15) * 4;
    }
    f32x4 acc[4][4];
#pragma unroll
    for (int a = 0; a < 4; ++a)
#pragma unroll
        for (int b = 0; b < 4; ++b) acc[a][b] = (f32x4){0.f, 0.f, 0.f, 0.f};
    f32x4 apf[8];
    int cpair = (tid & 63) * 2;
    int kkbase = tid >> 6;
    const float* wbase = W1 + (size_t)t * ND * NH + hc0 + cpair;
    f32x2 bpf[4][4];
    auto LOADA = [&](int k0) {
#pragma unroll
        for (int i = 0; i < 8; ++i)
            apf[i] = *(const f32x4*)(feat + aoff[i] + k0);
    };
    auto LOADB = [&](int k0) {
#pragma unroll
        for (int qq = 0; qq < 4; ++qq) {
            int d = k0 + (kkbase + qq * 4) * 4;
#pragma unroll
            for (int e = 0; e < 4; ++e)
                bpf[qq][e] = *(const f32x2*)(wbase + (size_t)(d + e) * NH);
        }
    };
    auto WRITEA = [&]() {
#pragma unroll
        for (int i = 0; i < 8; ++i) {
            int row = i * 16 + (tid >> 4);
            u32x2 v;
            v.x = packbf(apf[i][0], apf[i][1]);
            v.y = packbf(apf[i][2], apf[i][3]);
            *(u32x2*)(smem + swz(row * 128 + (tid & 15) * 8)) = v;
        }
    };
    auto WRITEB = [&]() {
#pragma unroll
        for (int qq = 0; qq < 4; ++qq) {
            int kk = kkbase + qq * 4;
#pragma unroll
            for (int j = 0; j < 2; ++j) {
                u32x2 v;
                v.x = packbf(bpf[qq][0][j], bpf[qq][1][j]);
                v.y = packbf(bpf[qq][2][j], bpf[qq][3][j]);
                *(u32x2*)(smem + 16384 + swz((cpair + j) * 128 + kk * 8)) = v;
            }
        }
    };
    auto COMPUTE_KS = [&](int ks) {
        int kbyte = ks * 64 + (lane >> 4) * 16;
        s16x8 af[4], bf[4];
#pragma unroll
        for (int f = 0; f < 4; ++f) {
            int rowA = wr * 64 + f * 16 + (lane & 15);
            af[f] = *(const s16x8*)(smem + swz(rowA * 128 + kbyte));
            int colB = wc * 64 + f * 16 + (lane & 15);
            bf[f] = *(const s16x8*)(smem + 16384 + swz(colB * 128 + kbyte));
        }
#pragma unroll
        for (int fm = 0; fm < 4; ++fm)
#pragma unroll
            for (int fn = 0; fn < 4; ++fn)
                acc[fm][fn] = __builtin_amdgcn_mfma_f32_16x16x32_bf16(
                    af[fm], bf[fn], acc[fm][fn], 0, 0, 0);
    };
    LOADA(0); LOADB(0);
    WRITEA(); WRITEB();
    __syncthreads();
#pragma unroll 1
    for (int kt = 0; kt < 20; ++kt) {
        bool nxt = (kt + 1 < 20);
        if (nxt) LOADA((kt + 1) * 64);
        COMPUTE_KS(0);
        if (nxt) LOADB((kt + 1) * 64);
        COMPUTE_KS(1);
        if (nxt) {
            __syncthreads();
            WRITEA(); WRITEB();
            __syncthreads();
        }
    }
    float part[4][4];
#pragma unroll
    for (int fm = 0; fm < 4; ++fm)
#pragma unroll
        for (int r = 0; r < 4; ++r) part[fm][r] = 0.f;
#pragma unroll
    for (int fn = 0; fn < 4; ++fn) {
        int h = hc0 + wc * 64 + fn * 16 + (lane & 15);
        float b1v = b1[t * NH + h];
        float w2v = w2[t * NH + h];
#pragma unroll
        for (int fm = 0; fm < 4; ++fm)
#pragma unroll
            for (int r = 0; r < 4; ++r) {
                float v = acc[fm][fn][r] + b1v;
                part[fm][r] += gelu_exact(v) * w2v;
            }
    }
#pragma unroll
    for (int m = 1; m <= 8; m <<= 1)
#pragma unroll
        for (int fm = 0; fm < 4; ++fm)
#pragma unroll
            for (int r = 0; r < 4; ++r)
                part[fm][r] += __shfl_xor(part[fm][r], m, 64);
    if ((lane & 15) == 0) {
        int slot = ct * 2 + wc;
#pragma unroll
        for (int fm = 0; fm < 4; ++fm)
#pragma unroll
            for (int r = 0; r < 4; ++r) {
                int row = wr * 64 + fm * 16 + (lane >> 4) * 4 + r;
                int gr = tilebase + row;
                if (gr < cnt) {
                    int s = perm[off_t + gr];
                    if (use_partials)
                        partials[(size_t)s * 8 + slot] = part[fm][r];
                    else
                        atomicAdd(&out[s], part[fm][r]);
                }
            }
    }
}

__global__ __launch_bounds__(256) void reduce_kernel(const float* __restrict__ partials,
        const int* __restrict__ idx, const float* __restrict__ b2,
        float* __restrict__ out) {
    int i = blockIdx.x * 256 + threadIdx.x;
    const float* p = partials + (size_t)i * 8;
    float s = b2[idx[i]];
#pragma unroll
    for (int j = 0; j < 8; ++j) s += p[j];
    out[i] = s;
}

extern "C" void kernel_launch(void* const* d_in, const int* in_sizes, int n_in,
                              void* d_out, int out_size, void* d_ws, size_t ws_size,
                              hipStream_t stream) {
    (void)in_sizes; (void)n_in; (void)out_size;
    const float* feat = (const float*)d_in[0];
    const int*   idx  = (const int*)d_in[1];
    const float* W1   = (const float*)d_in[2];
    const float* b1   = (const float*)d_in[3];
    const float* w2   = (const float*)d_in[4];
    const float* b2   = (const float*)d_in[5];
    float* out = (float*)d_out;

    char* ws = (char*)d_ws;
    int* counts  = (int*)ws;                                   // 64 B
    int* bc      = (int*)(ws + 64);                            // 4 KiB
    int* base    = (int*)(ws + 64 + 4096);                     // 4 KiB
    int* tmap    = (int*)(ws + 64 + 8192);                     // 64 B
    int* perm    = (int*)(ws + 128 + 8192);                    // 256 KiB
    float* partials = (float*)(ws + 128 + 8192 + (size_t)NB * 4);       // 2 MiB
    u16* Wfrag = (u16*)(ws + 128 + 8192 + (size_t)NB * 4 + (size_t)NB * 32); // 5.25 MiB
    size_t need_part = 128 + 8192 + (size_t)NB * 4 + (size_t)NB * 32;
    size_t need_full = need_part + (size_t)NT * ND * NH * 2;
    int use_partials = (ws_size >= need_part) ? 1 : 0;
    int use_wt = (ws_size >= need_full) ? 1 : 0;

    if (use_wt)
        fragw_kernel<<<320, 256, 0, stream>>>(W1, Wfrag);
    count_kernel<<<NB / 256, 256, 0, stream>>>(idx, bc);
    scan_kernel<<<1, 256, 0, stream>>>(bc, counts, base, tmap);
    scatter_kernel<<<NB / 256, 256, 0, stream>>>(idx, base, perm, b2, out);
    if (use_wt)
        gemm_c<<<2080, 256, 0, stream>>>(feat, Wfrag, b1, w2, perm, counts, tmap,
                                         partials, out, use_partials);
    else
        gemm_fallback<<<8192, 256, 0, stream>>>(feat, W1, b1, w2, perm, counts,
                                                partials, out, use_partials);
    if (use_partials)
        reduce_kernel<<<NB / 256, 256, 0, stream>>>(partials, idx, b2, out);
}